// Round 2
// baseline (3089.802 us; speedup 1.0000x reference)
//
#include <hip/hip_runtime.h>
#include <hip/hip_bf16.h>

typedef __attribute__((ext_vector_type(8))) short short8;
typedef __attribute__((ext_vector_type(4))) float floatx4;

#define NB 128
#define NP 196
#define NH 512
#define NV 32000
#define NT 19

__device__ __forceinline__ float bf2f(short s) {
  unsigned int u = ((unsigned int)(unsigned short)s) << 16;
  return __builtin_bit_cast(float, u);
}
__device__ __forceinline__ short f2bf(float f) {
  unsigned int u = __builtin_bit_cast(unsigned int, f);
  unsigned int lsb = (u >> 16) & 1u;
  u += 0x7fffu + lsb;
  return (short)(u >> 16);
}
__device__ __forceinline__ float sigf(float x) { return 1.f / (1.f + expf(-x)); }
// dual-mode scalar load: flag=1 -> bf16, flag=0 -> f32
__device__ __forceinline__ float ldw(int fl, const void* p, int i) {
  return fl ? bf2f(((const short*)p)[i]) : ((const float*)p)[i];
}

// ---------------- detect input dtype from features bit patterns ----------------
__global__ void k_detect(const unsigned int* __restrict__ w, int* __restrict__ flagp) {
  __shared__ int cnt;
  if (threadIdx.x == 0) cnt = 0;
  __syncthreads();
  int local = 0;
  for (int i = threadIdx.x; i < 4096; i += 256) {
    unsigned int lo = w[i] & 0xFFFFu;
    unsigned int ex = (lo >> 7) & 0xFFu;
    if (ex >= 110u && ex <= 135u) local++;
  }
  atomicAdd(&cnt, local);
  __syncthreads();
  if (threadIdx.x == 0) *flagp = (cnt > 2048) ? 1 : 0;
}

// ---------------- convert/copy a tensor into bf16 workspace ----------------
__global__ void k_conv(const void* __restrict__ src, short* __restrict__ dst, int n,
                       const int* __restrict__ flagp) {
  int fl = *flagp;
  int i = (blockIdx.x * 256 + threadIdx.x) * 8;
  if (i >= n) return;
  if (fl) {
    ((short8*)dst)[i >> 3] = ((const short8*)src)[i >> 3];
  } else {
    const float* s = (const float*)src + i;
    short8 o;
#pragma unroll
    for (int j = 0; j < 8; ++j) o[j] = f2bf(s[j]);
    ((short8*)dst)[i >> 3] = o;
  }
}

// ---------------- K0: fmean = mean_p features ----------------
__global__ void k_fmean(const short* __restrict__ feat, short* __restrict__ fmean) {
  int b = blockIdx.x;
  for (int e = threadIdx.x; e < NH; e += 256) {
    float s = 0.f;
    const short* fp = feat + (size_t)b * (NP * NH) + e;
    for (int p = 0; p < NP; ++p) s += bf2f(fp[p * NH]);
    fmean[b * NH + e] = f2bf(s * (1.f / 196.f));
  }
}

// ---------------- K1: h0/c0 init (M=128,N=1024,K=512) ----------------
__global__ void k_init(const short* __restrict__ fmean,
                       const short* __restrict__ w_init_h, const void* __restrict__ b_init_h,
                       const short* __restrict__ w_init_c, const void* __restrict__ b_init_c,
                       short* __restrict__ hbuf, float* __restrict__ cbuf,
                       const int* __restrict__ flagp) {
  int fl = *flagp;
  int wave = threadIdx.x >> 6, lane = threadIdx.x & 63;
  int rlo = lane & 15, quad = lane >> 4;
  int n = (blockIdx.x * 4 + wave) * 16 + rlo;
  const short* brow = (n < 512 ? w_init_h + (size_t)n * 512 : w_init_c + (size_t)(n - 512) * 512) + quad * 8;
  const short* arow = fmean + rlo * 512 + quad * 8;
  floatx4 acc[8];
#pragma unroll
  for (int mt = 0; mt < 8; ++mt) acc[mt] = (floatx4){0.f, 0.f, 0.f, 0.f};
  for (int k = 0; k < 512; k += 32) {
    short8 bfr = *(const short8*)(brow + k);
#pragma unroll
    for (int mt = 0; mt < 8; ++mt) {
      short8 afr = *(const short8*)(arow + mt * (16 * 512) + k);
      acc[mt] = __builtin_amdgcn_mfma_f32_16x16x32_bf16(afr, bfr, acc[mt], 0, 0, 0);
    }
  }
  float bias = (n < 512) ? ldw(fl, b_init_h, n) : ldw(fl, b_init_c, n - 512);
#pragma unroll
  for (int mt = 0; mt < 8; ++mt)
#pragma unroll
    for (int r = 0; r < 4; ++r) {
      int bb = mt * 16 + quad * 4 + r;
      float v = acc[mt][r] + bias;
      if (n < 512) hbuf[bb * 512 + n] = f2bf(v);
      else cbuf[bb * 512 + (n - 512)] = v;
    }
}

// ---------------- K2: att1 = features @ w_enc^T + b (M=25088,N=512,K=512) ----------------
__global__ void k_att1(const short* __restrict__ feat, const short* __restrict__ w_enc,
                       const void* __restrict__ b_enc, short* __restrict__ att1,
                       const int* __restrict__ flagp) {
  int fl = *flagp;
  int wave = threadIdx.x >> 6, lane = threadIdx.x & 63;
  int rlo = lane & 15, quad = lane >> 4;
  int n = (blockIdx.x * 4 + wave) * 16 + rlo;
  int mbase = blockIdx.y * 128;
  const short* brow = w_enc + (size_t)n * 512 + quad * 8;
  const short* arow = feat + (size_t)(mbase + rlo) * 512 + quad * 8;
  floatx4 acc[8];
#pragma unroll
  for (int mt = 0; mt < 8; ++mt) acc[mt] = (floatx4){0.f, 0.f, 0.f, 0.f};
  for (int k = 0; k < 512; k += 32) {
    short8 bfr = *(const short8*)(brow + k);
#pragma unroll
    for (int mt = 0; mt < 8; ++mt) {
      short8 afr = *(const short8*)(arow + (size_t)mt * (16 * 512) + k);
      acc[mt] = __builtin_amdgcn_mfma_f32_16x16x32_bf16(afr, bfr, acc[mt], 0, 0, 0);
    }
  }
  float bias = ldw(fl, b_enc, n);
#pragma unroll
  for (int mt = 0; mt < 8; ++mt)
#pragma unroll
    for (int r = 0; r < 4; ++r) {
      int m = mbase + mt * 16 + quad * 4 + r;
      att1[(size_t)m * 512 + n] = f2bf(acc[mt][r] + bias);
    }
}

// ---------------- K3: xpart[t,b,:] = emb @ w_ih[:, :512]^T + b_ih + b_hh ----------------
__global__ void k_xpart(const int* __restrict__ captions, const short* __restrict__ embed_w,
                        const short* __restrict__ w_ih, const void* __restrict__ b_ih,
                        const void* __restrict__ b_hh, float* __restrict__ xp,
                        const int* __restrict__ flagp) {
  int fl = *flagp;
  int wave = threadIdx.x >> 6, lane = threadIdx.x & 63;
  int rlo = lane & 15, quad = lane >> 4;
  int t = blockIdx.y;
  int n = (blockIdx.x * 4 + wave) * 16 + rlo;
  const short* brow = w_ih + (size_t)n * 1024 + quad * 8;
  int tok[8];
#pragma unroll
  for (int mt = 0; mt < 8; ++mt) tok[mt] = captions[(mt * 16 + rlo) * 20 + t];
  floatx4 acc[8];
#pragma unroll
  for (int mt = 0; mt < 8; ++mt) acc[mt] = (floatx4){0.f, 0.f, 0.f, 0.f};
  for (int k = 0; k < 512; k += 32) {
    short8 bfr = *(const short8*)(brow + k);
#pragma unroll
    for (int mt = 0; mt < 8; ++mt) {
      short8 afr = *(const short8*)(embed_w + (size_t)tok[mt] * 512 + quad * 8 + k);
      acc[mt] = __builtin_amdgcn_mfma_f32_16x16x32_bf16(afr, bfr, acc[mt], 0, 0, 0);
    }
  }
  float bias = ldw(fl, b_ih, n) + ldw(fl, b_hh, n);
#pragma unroll
  for (int mt = 0; mt < 8; ++mt)
#pragma unroll
    for (int r = 0; r < 4; ++r) {
      int bb = mt * 16 + quad * 4 + r;
      xp[((size_t)t * 128 + bb) * 2048 + n] = acc[mt][r] + bias;
    }
}

// ---------------- KA: abuf = h @ [w_dec|w_beta|w_hh]^T (+biases) ----------------
__global__ void k_hproj(const short* __restrict__ hbuf,
                        const short* __restrict__ w_dec, const void* __restrict__ b_dec,
                        const short* __restrict__ w_beta, const void* __restrict__ b_beta,
                        const short* __restrict__ w_hh, float* __restrict__ abuf,
                        const int* __restrict__ flagp) {
  int fl = *flagp;
  int wave = threadIdx.x >> 6, lane = threadIdx.x & 63;
  int rlo = lane & 15, quad = lane >> 4;
  int n = (blockIdx.x * 4 + wave) * 16 + rlo;  // 0..3071
  const short* brow;
  float bias;
  if (n < 512)       { brow = w_dec  + (size_t)n * 512;          bias = ldw(fl, b_dec, n); }
  else if (n < 1024) { brow = w_beta + (size_t)(n - 512) * 512;  bias = ldw(fl, b_beta, n - 512); }
  else               { brow = w_hh   + (size_t)(n - 1024) * 512; bias = 0.f; }
  brow += quad * 8;
  const short* arow = hbuf + rlo * 512 + quad * 8;
  floatx4 acc[8];
#pragma unroll
  for (int mt = 0; mt < 8; ++mt) acc[mt] = (floatx4){0.f, 0.f, 0.f, 0.f};
  for (int k = 0; k < 512; k += 32) {
    short8 bfr = *(const short8*)(brow + k);
#pragma unroll
    for (int mt = 0; mt < 8; ++mt) {
      short8 afr = *(const short8*)(arow + mt * (16 * 512) + k);
      acc[mt] = __builtin_amdgcn_mfma_f32_16x16x32_bf16(afr, bfr, acc[mt], 0, 0, 0);
    }
  }
#pragma unroll
  for (int mt = 0; mt < 8; ++mt)
#pragma unroll
    for (int r = 0; r < 4; ++r) {
      int bb = mt * 16 + quad * 4 + r;
      abuf[(size_t)bb * 3072 + n] = acc[mt][r] + bias;
    }
}

// ---------------- KB: attention scores + softmax + context, per batch-row ----------------
__global__ void k_attn(const short* __restrict__ att1, const short* __restrict__ feat,
                       const void* __restrict__ w_full, const float* __restrict__ abuf,
                       const int* __restrict__ lengths, short* __restrict__ awe_bf,
                       void* __restrict__ d_out, const int* __restrict__ flagp, int t) {
  int fl = *flagp;
  int b = blockIdx.x;
  int tid = threadIdx.x, wave = tid >> 6, lane = tid & 63;
  float att2r[8], wfr[8];
#pragma unroll
  for (int j = 0; j < 8; ++j) {
    int a = lane + j * 64;
    att2r[j] = abuf[(size_t)b * 3072 + a];
    wfr[j] = ldw(fl, w_full, a);
  }
  __shared__ float sm[196];
  for (int p = wave; p < NP; p += 4) {
    const short* arow = att1 + ((size_t)b * NP + p) * 512;
    float s = 0.f;
#pragma unroll
    for (int j = 0; j < 8; ++j) {
      float v = bf2f(arow[lane + j * 64]) + att2r[j];
      s += fmaxf(v, 0.f) * wfr[j];
    }
#pragma unroll
    for (int off = 32; off >= 1; off >>= 1) s += __shfl_xor(s, off, 64);
    if (lane == 0) sm[p] = s;
  }
  __syncthreads();
  bool act = t < (lengths[b] - 1);
  if (wave == 0) {
    float v0 = sm[lane], v1 = sm[lane + 64], v2 = sm[lane + 128];
    float v3 = (lane < 4) ? sm[lane + 192] : -1e30f;
    float m = fmaxf(fmaxf(v0, v1), fmaxf(v2, v3));
#pragma unroll
    for (int off = 32; off >= 1; off >>= 1) m = fmaxf(m, __shfl_xor(m, off, 64));
    float e0 = expf(v0 - m), e1 = expf(v1 - m), e2 = expf(v2 - m);
    float e3 = (lane < 4) ? expf(v3 - m) : 0.f;
    float s = e0 + e1 + e2 + e3;
#pragma unroll
    for (int off = 32; off >= 1; off >>= 1) s += __shfl_xor(s, off, 64);
    float inv = 1.f / s;
    float a0 = e0 * inv, a1 = e1 * inv, a2 = e2 * inv, a3 = e3 * inv;
    sm[lane] = a0; sm[lane + 64] = a1; sm[lane + 128] = a2;
    if (lane < 4) sm[lane + 192] = a3;
    size_t ob = (size_t)NB * NT * NV + ((size_t)b * NT + t) * NP;
    float o0 = act ? a0 : 0.f, o1 = act ? a1 : 0.f, o2 = act ? a2 : 0.f, o3 = act ? a3 : 0.f;
    if (fl) {
      short* op = (short*)d_out;
      op[ob + lane] = f2bf(o0); op[ob + lane + 64] = f2bf(o1); op[ob + lane + 128] = f2bf(o2);
      if (lane < 4) op[ob + lane + 192] = f2bf(o3);
    } else {
      float* op = (float*)d_out;
      op[ob + lane] = o0; op[ob + lane + 64] = o1; op[ob + lane + 128] = o2;
      if (lane < 4) op[ob + lane + 192] = o3;
    }
  }
  __syncthreads();
  for (int e = tid; e < NH; e += 256) {
    float s = 0.f;
    const short* fp = feat + (size_t)b * NP * NH + e;
    for (int p = 0; p < NP; ++p) s += sm[p] * bf2f(fp[p * NH]);
    float gate = sigf(abuf[(size_t)b * 3072 + 512 + e]);
    awe_bf[b * NH + e] = f2bf(gate * s);
  }
}

// ---------------- KC: gates GEMM + LSTM pointwise (fused) ----------------
__global__ void k_gates_lstm(const short* __restrict__ awe_bf, const short* __restrict__ w_ih,
                             const float* __restrict__ xp, const float* __restrict__ abuf,
                             const int* __restrict__ lengths, float* __restrict__ cbuf,
                             short* __restrict__ hbuf, short* __restrict__ hnbuf, int t) {
  int tid = threadIdx.x, wave = tid >> 6, lane = tid & 63;
  int rlo = lane & 15, quad = lane >> 4;
  int n = wave * 512 + blockIdx.x * 16 + rlo;  // gate g=wave, 16-col slice
  const short* brow = w_ih + (size_t)n * 1024 + 512 + quad * 8;
  const short* arow = awe_bf + rlo * 512 + quad * 8;
  floatx4 acc[8];
#pragma unroll
  for (int mt = 0; mt < 8; ++mt) acc[mt] = (floatx4){0.f, 0.f, 0.f, 0.f};
  for (int k = 0; k < 512; k += 32) {
    short8 bfr = *(const short8*)(brow + k);
#pragma unroll
    for (int mt = 0; mt < 8; ++mt) {
      short8 afr = *(const short8*)(arow + mt * (16 * 512) + k);
      acc[mt] = __builtin_amdgcn_mfma_f32_16x16x32_bf16(afr, bfr, acc[mt], 0, 0, 0);
    }
  }
  __shared__ float gsm[4][128][17];  // +1 pad: kill bank conflicts
#pragma unroll
  for (int mt = 0; mt < 8; ++mt)
#pragma unroll
    for (int r = 0; r < 4; ++r) {
      int bb = mt * 16 + quad * 4 + r;
      float v = acc[mt][r] + xp[((size_t)t * 128 + bb) * 2048 + n] + abuf[(size_t)bb * 3072 + 1024 + n];
      gsm[wave][bb][rlo] = v;
    }
  __syncthreads();
  for (int idx = tid; idx < 2048; idx += 256) {
    int bb = idx >> 4, jl = idx & 15;
    int j = blockIdx.x * 16 + jl;
    float ig = gsm[0][bb][jl], fg = gsm[1][bb][jl], gg = gsm[2][bb][jl], og = gsm[3][bb][jl];
    float co = cbuf[bb * 512 + j];
    float cn = sigf(fg) * co + sigf(ig) * tanhf(gg);
    float hn = sigf(og) * tanhf(cn);
    hnbuf[bb * 512 + j] = f2bf(hn);
    if (t < lengths[bb] - 1) {
      cbuf[bb * 512 + j] = cn;
      hbuf[bb * 512 + j] = f2bf(hn);
    }
  }
}

// ---------------- KE: preds = h_new @ w_fc^T + b_fc, masked (M=128,N=32000,K=512) ----------------
__global__ void k_preds(const short* __restrict__ hnbuf, const short* __restrict__ w_fc,
                        const void* __restrict__ b_fc, const int* __restrict__ lengths,
                        void* __restrict__ d_out, const int* __restrict__ flagp, int t) {
  int fl = *flagp;
  int wave = threadIdx.x >> 6, lane = threadIdx.x & 63;
  int rlo = lane & 15, quad = lane >> 4;
  int n = (blockIdx.x * 4 + wave) * 16 + rlo;
  const short* brow = w_fc + (size_t)n * 512 + quad * 8;
  const short* arow = hnbuf + rlo * 512 + quad * 8;
  floatx4 acc[8];
#pragma unroll
  for (int mt = 0; mt < 8; ++mt) acc[mt] = (floatx4){0.f, 0.f, 0.f, 0.f};
  for (int k = 0; k < 512; k += 32) {
    short8 bfr = *(const short8*)(brow + k);
#pragma unroll
    for (int mt = 0; mt < 8; ++mt) {
      short8 afr = *(const short8*)(arow + mt * (16 * 512) + k);
      acc[mt] = __builtin_amdgcn_mfma_f32_16x16x32_bf16(afr, bfr, acc[mt], 0, 0, 0);
    }
  }
  float bias = ldw(fl, b_fc, n);
#pragma unroll
  for (int mt = 0; mt < 8; ++mt)
#pragma unroll
    for (int r = 0; r < 4; ++r) {
      int bb = mt * 16 + quad * 4 + r;
      bool act = t < lengths[bb] - 1;
      float v = act ? (acc[mt][r] + bias) : 0.f;
      size_t oi = ((size_t)bb * NT + t) * NV + n;
      if (fl) ((short*)d_out)[oi] = f2bf(v);
      else ((float*)d_out)[oi] = v;
    }
}

extern "C" void kernel_launch(void* const* d_in, const int* in_sizes, int n_in,
                              void* d_out, int out_size, void* d_ws, size_t ws_size,
                              hipStream_t stream) {
  const void* features = d_in[0];
  const int* captions = (const int*)d_in[1];
  const int* lengths = (const int*)d_in[2];
  const void* w_enc_att = d_in[3];
  const void* b_enc_att = d_in[4];
  const void* w_dec_att = d_in[5];
  const void* b_dec_att = d_in[6];
  const void* w_full = d_in[7];
  const void* embed_w = d_in[9];
  const void* w_ih = d_in[10];
  const void* b_ih = d_in[11];
  const void* w_hh = d_in[12];
  const void* b_hh = d_in[13];
  const void* w_init_h = d_in[14];
  const void* b_init_h = d_in[15];
  const void* w_init_c = d_in[16];
  const void* b_init_c = d_in[17];
  const void* w_beta = d_in[18];
  const void* b_beta = d_in[19];
  const void* w_fc = d_in[20];
  const void* b_fc = d_in[21];

  char* ws = (char*)d_ws;
  int* flagp = (int*)ws; ws += 16;
  short* cfeat = (short*)ws; ws += (size_t)12845056 * 2;
  short* cembed = (short*)ws; ws += (size_t)16384000 * 2;
  short* cwfc = (short*)ws; ws += (size_t)16384000 * 2;
  short* cwih = (short*)ws; ws += (size_t)2097152 * 2;
  short* cwhh = (short*)ws; ws += (size_t)1048576 * 2;
  short* cwenc = (short*)ws; ws += (size_t)262144 * 2;
  short* cwdec = (short*)ws; ws += (size_t)262144 * 2;
  short* cwbeta = (short*)ws; ws += (size_t)262144 * 2;
  short* cwinith = (short*)ws; ws += (size_t)262144 * 2;
  short* cwinitc = (short*)ws; ws += (size_t)262144 * 2;
  short* att1 = (short*)ws; ws += (size_t)25088 * 512 * 2;
  float* xp   = (float*)ws; ws += (size_t)2432 * 2048 * 4;
  float* abuf = (float*)ws; ws += (size_t)128 * 3072 * 4;
  short* hbuf = (short*)ws; ws += 128 * 512 * 2;
  short* hnbuf = (short*)ws; ws += 128 * 512 * 2;
  short* awe  = (short*)ws; ws += 128 * 512 * 2;
  short* fmean = (short*)ws; ws += 128 * 512 * 2;
  float* cbuf = (float*)ws; ws += 128 * 512 * 4;

  k_detect<<<1, 256, 0, stream>>>((const unsigned int*)features, flagp);

#define CONV(src, dst, n) k_conv<<<((n)/8 + 255)/256, 256, 0, stream>>>(src, dst, n, flagp)
  CONV(features, cfeat, 12845056);
  CONV(embed_w, cembed, 16384000);
  CONV(w_fc, cwfc, 16384000);
  CONV(w_ih, cwih, 2097152);
  CONV(w_hh, cwhh, 1048576);
  CONV(w_enc_att, cwenc, 262144);
  CONV(w_dec_att, cwdec, 262144);
  CONV(w_beta, cwbeta, 262144);
  CONV(w_init_h, cwinith, 262144);
  CONV(w_init_c, cwinitc, 262144);
#undef CONV

  k_fmean<<<128, 256, 0, stream>>>(cfeat, fmean);
  k_att1<<<dim3(8, 196), 256, 0, stream>>>(cfeat, cwenc, b_enc_att, att1, flagp);
  k_xpart<<<dim3(32, NT), 256, 0, stream>>>(captions, cembed, cwih, b_ih, b_hh, xp, flagp);
  k_init<<<16, 256, 0, stream>>>(fmean, cwinith, b_init_h, cwinitc, b_init_c, hbuf, cbuf, flagp);

  for (int t = 0; t < NT; ++t) {
    k_hproj<<<48, 256, 0, stream>>>(hbuf, cwdec, b_dec_att, cwbeta, b_beta, cwhh, abuf, flagp);
    k_attn<<<128, 256, 0, stream>>>(att1, cfeat, w_full, abuf, lengths, awe, d_out, flagp, t);
    k_gates_lstm<<<32, 256, 0, stream>>>(awe, cwih, xp, abuf, lengths, cbuf, hbuf, hnbuf, t);
    k_preds<<<500, 256, 0, stream>>>(hnbuf, cwfc, b_fc, lengths, d_out, flagp, t);
  }
}